// Round 1
// baseline (2443.138 us; speedup 1.0000x reference)
//
#include <hip/hip_runtime.h>
#include <math.h>

// ---------- helpers ----------
static __device__ __forceinline__ float4 relu4(float4 a, float4 b) {  // relu(a+b)
    float4 r;
    r.x = fmaxf(a.x + b.x, 0.f);
    r.y = fmaxf(a.y + b.y, 0.f);
    r.z = fmaxf(a.z + b.z, 0.f);
    r.w = fmaxf(a.w + b.w, 0.f);
    return r;
}

// ---------- kernels ----------
__global__ __launch_bounds__(256) void k_zero(float* __restrict__ p, int n) {
    int i = blockIdx.x * 256 + threadIdx.x;
    if (i < n) p[i] = 0.f;
}

// degree counts for all three scatter targets in one pass
__global__ __launch_bounds__(256) void k_deg(const int* __restrict__ d1,
                                             const int* __restrict__ s2,
                                             const int* __restrict__ d2,
                                             float* deg1, float* deg2f, float* deg2r,
                                             int E1, int E2) {
    int e = blockIdx.x * 256 + threadIdx.x;
    if (e < E1) unsafeAtomicAdd(deg1 + d1[e], 1.f);
    if (e < E2) {
        unsafeAtomicAdd(deg2f + d2[e], 1.f);
        unsafeAtomicAdd(deg2r + s2[e], 1.f);
    }
}

// deg -> dinv = 1/sqrt(deg + 1)   (+1 = self loop)
__global__ __launch_bounds__(256) void k_rsqrt(float* __restrict__ p, int n) {
    int i = blockIdx.x * 256 + threadIdx.x;
    if (i < n) p[i] = 1.f / sqrtf(p[i] + 1.f);
}

// xw1[i] = emb[x[i]] @ W1 ; out1[i] = xw1[i] * dinv1[i]^2  (self-loop init)
// block = 256: c = tid&31 (out col), rg = tid>>5 (row group of 4)
__global__ __launch_bounds__(256) void k_xw1(const int* __restrict__ x,
                                             const float* __restrict__ emb,
                                             const float* __restrict__ W1,
                                             const float* __restrict__ dinv1,
                                             float* __restrict__ xw1,
                                             float* __restrict__ out1, int N) {
    int c = threadIdx.x & 31, rg = threadIdx.x >> 5;
    int r0 = blockIdx.x * 32 + rg * 4;
    int xi[4];
    float acc[4] = {0.f, 0.f, 0.f, 0.f};
#pragma unroll
    for (int j = 0; j < 4; j++) {
        int r = r0 + j;
        xi[j] = (r < N) ? x[r] * 64 : 0;  // float4 row base (256 floats = 64 float4)
    }
    const float4* emb4 = (const float4*)emb;
    for (int k = 0; k < 256; k += 4) {
        float w0 = W1[k * 32 + c], w1 = W1[k * 32 + 32 + c];
        float w2 = W1[k * 32 + 64 + c], w3 = W1[k * 32 + 96 + c];
        int kq = k >> 2;
#pragma unroll
        for (int j = 0; j < 4; j++) {
            float4 e = emb4[xi[j] + kq];  // broadcast across the 32 lanes of a row group
            acc[j] = fmaf(e.x, w0, fmaf(e.y, w1, fmaf(e.z, w2, fmaf(e.w, w3, acc[j]))));
        }
    }
#pragma unroll
    for (int j = 0; j < 4; j++) {
        int r = r0 + j;
        if (r < N) {
            float dv = dinv1[r];
            float v = acc[j];
            xw1[r * 32 + c] = v;
            out1[r * 32 + c] = v * dv * dv;
        }
    }
}

// GCN1 edge scatter: out1[v] += xw1[u] * dinv1[u]*dinv1[v].  8 lanes/edge, float4 read.
__global__ __launch_bounds__(256) void k_edge1(const int* __restrict__ src,
                                               const int* __restrict__ dst,
                                               const float* __restrict__ dinv1,
                                               const float* __restrict__ xw1,
                                               float* out1, int E) {
    int gid = blockIdx.x * 256 + threadIdx.x;
    int e = gid >> 3, q = gid & 7;
    if (e >= E) return;
    int u = src[e], v = dst[e];
    float w = dinv1[u] * dinv1[v];
    float4 xv = ((const float4*)xw1)[u * 8 + q];
    float* o = out1 + v * 32 + q * 4;
    unsafeAtomicAdd(o + 0, xv.x * w);
    unsafeAtomicAdd(o + 1, xv.y * w);
    unsafeAtomicAdd(o + 2, xv.z * w);
    unsafeAtomicAdd(o + 3, xv.w * w);
}

// Fused: hp[p] = relu(out1[pos0]+b1) * relu(out1[pos1]+b1)   (never materialized)
//        xwa = hp @ W2a ; xwb = hp @ W2b ; self-loop init of out2a/out2b
__global__ __launch_bounds__(256) void k_xw2(const int* __restrict__ pos,
                                             const float* __restrict__ out1,
                                             const float* __restrict__ b1,
                                             const float* __restrict__ W2a,
                                             const float* __restrict__ W2b,
                                             const float* __restrict__ dinv2f,
                                             const float* __restrict__ dinv2r,
                                             float* __restrict__ xwa, float* __restrict__ xwb,
                                             float* __restrict__ o2a, float* __restrict__ o2b) {
    int c = threadIdx.x & 31, rg = threadIdx.x >> 5;
    int p0 = blockIdx.x * 32 + rg * 4;
    int pa[4], pb[4];
#pragma unroll
    for (int j = 0; j < 4; j++) {
        pa[j] = pos[2 * (p0 + j)] * 8;      // float4 row base of out1
        pb[j] = pos[2 * (p0 + j) + 1] * 8;
    }
    float aa[4] = {0, 0, 0, 0}, ab[4] = {0, 0, 0, 0};
    const float4* o14 = (const float4*)out1;
    const float4* b14 = (const float4*)b1;
    for (int k = 0; k < 32; k += 4) {
        int kq = k >> 2;
        float4 bq = b14[kq];
        float wa0 = W2a[k * 32 + c], wa1 = W2a[k * 32 + 32 + c];
        float wa2 = W2a[k * 32 + 64 + c], wa3 = W2a[k * 32 + 96 + c];
        float wb0 = W2b[k * 32 + c], wb1 = W2b[k * 32 + 32 + c];
        float wb2 = W2b[k * 32 + 64 + c], wb3 = W2b[k * 32 + 96 + c];
#pragma unroll
        for (int j = 0; j < 4; j++) {
            float4 ea = relu4(o14[pa[j] + kq], bq);
            float4 eb = relu4(o14[pb[j] + kq], bq);
            float hx = ea.x * eb.x, hy = ea.y * eb.y, hz = ea.z * eb.z, hw = ea.w * eb.w;
            aa[j] = fmaf(hx, wa0, fmaf(hy, wa1, fmaf(hz, wa2, fmaf(hw, wa3, aa[j]))));
            ab[j] = fmaf(hx, wb0, fmaf(hy, wb1, fmaf(hz, wb2, fmaf(hw, wb3, ab[j]))));
        }
    }
#pragma unroll
    for (int j = 0; j < 4; j++) {
        int p = p0 + j;
        float da = dinv2f[p], db = dinv2r[p];
        xwa[p * 32 + c] = aa[j];
        o2a[p * 32 + c] = aa[j] * da * da;
        xwb[p * 32 + c] = ab[j];
        o2b[p * 32 + c] = ab[j] * db * db;
    }
}

// GCN2 both directions in one pass:
//   out2a[v] += xwa[u] * dinv2f[u]*dinv2f[v]   (edges src=u, dst=v)
//   out2b[u] += xwb[v] * dinv2r[v]*dinv2r[u]   (reversed)
__global__ __launch_bounds__(256) void k_edge2(const int* __restrict__ s2,
                                               const int* __restrict__ d2,
                                               const float* __restrict__ dinv2f,
                                               const float* __restrict__ dinv2r,
                                               const float* __restrict__ xwa,
                                               const float* __restrict__ xwb,
                                               float* o2a, float* o2b, int E) {
    int gid = blockIdx.x * 256 + threadIdx.x;
    int e = gid >> 3, q = gid & 7;
    if (e >= E) return;
    int u = s2[e], v = d2[e];
    float wa = dinv2f[u] * dinv2f[v];
    float wb = dinv2r[u] * dinv2r[v];
    float4 xa = ((const float4*)xwa)[u * 8 + q];
    float4 xb = ((const float4*)xwb)[v * 8 + q];
    float* oa = o2a + v * 32 + q * 4;
    float* ob = o2b + u * 32 + q * 4;
    unsafeAtomicAdd(oa + 0, xa.x * wa);
    unsafeAtomicAdd(oa + 1, xa.y * wa);
    unsafeAtomicAdd(oa + 2, xa.z * wa);
    unsafeAtomicAdd(oa + 3, xa.w * wa);
    unsafeAtomicAdd(ob + 0, xb.x * wb);
    unsafeAtomicAdd(ob + 1, xb.y * wb);
    unsafeAtomicAdd(ob + 2, xb.z * wb);
    unsafeAtomicAdd(ob + 3, xb.w * wb);
}

// Final: h3[p] = relu(out2a[p]+b2a) + relu(out2b[p]+b2b)
//        out[q] = (h3[idx[2q]] * h3[idx[2q+1]]) . Wp + bp
// 8 lanes per output, shuffle reduce.
__global__ __launch_bounds__(256) void k_final(const int* __restrict__ idx,
                                               const float* __restrict__ o2a,
                                               const float* __restrict__ o2b,
                                               const float* __restrict__ b2a,
                                               const float* __restrict__ b2b,
                                               const float* __restrict__ Wp,
                                               const float* __restrict__ bp,
                                               float* __restrict__ out, int Q) {
    int gid = blockIdx.x * 256 + threadIdx.x;
    int qi = gid >> 3, q = gid & 7;
    if (qi >= Q) return;
    int i0 = idx[2 * qi] * 8, i1 = idx[2 * qi + 1] * 8;
    float4 ba = ((const float4*)b2a)[q];
    float4 bb = ((const float4*)b2b)[q];
    float4 wp = ((const float4*)Wp)[q];
    const float4* A = (const float4*)o2a;
    const float4* B = (const float4*)o2b;
    float4 h0a = relu4(A[i0 + q], ba), h0b = relu4(B[i0 + q], bb);
    float4 h1a = relu4(A[i1 + q], ba), h1b = relu4(B[i1 + q], bb);
    float s = (h0a.x + h0b.x) * (h1a.x + h1b.x) * wp.x
            + (h0a.y + h0b.y) * (h1a.y + h1b.y) * wp.y
            + (h0a.z + h0b.z) * (h1a.z + h1b.z) * wp.z
            + (h0a.w + h0b.w) * (h1a.w + h1b.w) * wp.w;
    s += __shfl_xor(s, 1);
    s += __shfl_xor(s, 2);
    s += __shfl_xor(s, 4);
    if (q == 0) out[qi] = s + bp[0];
}

// ---------- launch ----------
extern "C" void kernel_launch(void* const* d_in, const int* in_sizes, int n_in,
                              void* d_out, int out_size, void* d_ws, size_t ws_size,
                              hipStream_t stream) {
    const int* x    = (const int*)d_in[0];
    const int* e1   = (const int*)d_in[1];   // [2, E1]
    const int* pos  = (const int*)d_in[2];   // [NP, 2]
    const int* idx  = (const int*)d_in[3];   // [NP]
    const int* e2   = (const int*)d_in[4];   // [2, E2]
    const float* emb = (const float*)d_in[5];
    const float* W1  = (const float*)d_in[6];
    const float* b1  = (const float*)d_in[7];
    const float* W2a = (const float*)d_in[8];
    const float* b2a = (const float*)d_in[9];
    const float* W2b = (const float*)d_in[10];
    const float* b2b = (const float*)d_in[11];
    const float* Wp  = (const float*)d_in[12];
    const float* bp  = (const float*)d_in[13];

    const int N1 = in_sizes[0];        // 50000 nodes
    const int E1 = in_sizes[1] / 2;    // 1600000
    const int NP = in_sizes[3];        // 200000 pair-nodes
    const int E2 = in_sizes[4] / 2;    // 1600000
    const int Q  = out_size;           // 100000

    // workspace layout (floats), all 64B-aligned
    float* ws = (float*)d_ws;
    size_t o = 0;
    auto alloc = [&](size_t n) { size_t r = o; o += (n + 15) & ~(size_t)15; return r; };
    float* dinv1  = ws + alloc(N1);        // deg1 -> dinv1
    float* dinv2f = ws + alloc(NP);
    float* dinv2r = ws + alloc(NP);
    const int nDeg = (int)o;               // contiguous zero/rsqrt region
    float* xw1  = ws + alloc((size_t)N1 * 32);
    float* out1 = ws + alloc((size_t)N1 * 32);
    float* xwa  = ws + alloc((size_t)NP * 32);
    float* xwb  = ws + alloc((size_t)NP * 32);
    float* o2a  = ws + alloc((size_t)NP * 32);
    float* o2b  = ws + alloc((size_t)NP * 32);
    (void)ws_size; (void)n_in;  // requires ~112 MiB of ws

    const int B = 256;
    // 1) zero degree region
    k_zero<<<(nDeg + B - 1) / B, B, 0, stream>>>(ws, nDeg);
    // 2) degree counts (deg1 from e1 dst; deg2f from e2 dst; deg2r from e2 src)
    int Emax = (E1 > E2 ? E1 : E2);
    k_deg<<<(Emax + B - 1) / B, B, 0, stream>>>(e1 + E1, e2, e2 + E2,
                                                dinv1, dinv2f, dinv2r, E1, E2);
    // 3) dinv = rsqrt(deg+1)
    k_rsqrt<<<(nDeg + B - 1) / B, B, 0, stream>>>(ws, nDeg);
    // 4) xw1 = emb[x] @ W1 ; out1 = self-loop init
    k_xw1<<<(N1 + 31) / 32, B, 0, stream>>>(x, emb, W1, dinv1, xw1, out1, N1);
    // 5) GCN1 edge scatter
    k_edge1<<<((size_t)E1 * 8 + B - 1) / B, B, 0, stream>>>(e1, e1 + E1, dinv1, xw1, out1, E1);
    // 6) pair-product + GEMMs + self-loop init for GCN2
    k_xw2<<<(NP + 31) / 32, B, 0, stream>>>(pos, out1, b1, W2a, W2b, dinv2f, dinv2r,
                                            xwa, xwb, o2a, o2b);
    // 7) GCN2 edge scatter (both directions)
    k_edge2<<<((size_t)E2 * 8 + B - 1) / B, B, 0, stream>>>(e2, e2 + E2, dinv2f, dinv2r,
                                                            xwa, xwb, o2a, o2b, E2);
    // 8) final gather + pair product + projection
    k_final<<<((size_t)Q * 8 + B - 1) / B, B, 0, stream>>>(idx, o2a, o2b, b2a, b2b, Wp, bp,
                                                           (float*)d_out, Q);
}

// Round 2
// 1013.512 us; speedup vs baseline: 2.4106x; 2.4106x over previous
//
#include <hip/hip_runtime.h>
#include <math.h>

// ------------------------------------------------------------------
// LocalWLNet: emb-gather+GEMM -> GCN1 -> pair-product+2xGEMM -> GCN2(fwd+rev)
// -> gather+pair-product+projection.
// R2: atomic edge-scatter replaced by counting-sort CSR + gather.
// ------------------------------------------------------------------

static __device__ __forceinline__ float4 relu4(float4 a, float4 b) {  // relu(a+b)
    float4 r;
    r.x = fmaxf(a.x + b.x, 0.f);
    r.y = fmaxf(a.y + b.y, 0.f);
    r.z = fmaxf(a.z + b.z, 0.f);
    r.w = fmaxf(a.w + b.w, 0.f);
    return r;
}

__global__ __launch_bounds__(256) void k_zero_i(int* __restrict__ p, int n) {
    int i = blockIdx.x * 256 + threadIdx.x;
    if (i < n) p[i] = 0;
}

// int histograms of the three scatter destinations in one pass
__global__ __launch_bounds__(256) void k_deg(const int* __restrict__ d1,
                                             const int* __restrict__ s2,
                                             const int* __restrict__ d2,
                                             int* c1, int* c2f, int* c2r,
                                             int E1, int E2) {
    int e = blockIdx.x * 256 + threadIdx.x;
    if (e < E1) atomicAdd(c1 + d1[e], 1);
    if (e < E2) {
        atomicAdd(c2f + d2[e], 1);
        atomicAdd(c2r + s2[e], 1);
    }
}

// dinv = 1/sqrt(cnt + 1)   (+1 = self loop)
__global__ __launch_bounds__(256) void k_dinv(const int* __restrict__ cnt,
                                              float* __restrict__ dinv, int n) {
    int i = blockIdx.x * 256 + threadIdx.x;
    if (i < n) dinv[i] = 1.f / sqrtf((float)cnt[i] + 1.f);
}

// ---- exclusive scan (3-kernel, chunk = 2048 per block) ----
#define SCAN_CHUNK 2048
__global__ __launch_bounds__(256) void k_scan1(const int* __restrict__ in, int* __restrict__ out,
                                               int* __restrict__ bsum, int n) {
    __shared__ int buf[SCAN_CHUNK];
    __shared__ int wsum[4];
    int base = blockIdx.x * SCAN_CHUNK;
#pragma unroll
    for (int r = 0; r < 8; r++) {
        int i = base + r * 256 + threadIdx.x;
        buf[r * 256 + threadIdx.x] = (i < n) ? in[i] : 0;
    }
    __syncthreads();
    int v[8];
    int s = 0;
#pragma unroll
    for (int j = 0; j < 8; j++) {
        v[j] = buf[threadIdx.x * 8 + j];
        s += v[j];
    }
    int own = s;
    int lane = threadIdx.x & 63, wid = threadIdx.x >> 6;
#pragma unroll
    for (int d = 1; d < 64; d <<= 1) {
        int t = __shfl_up(s, d, 64);
        if (lane >= d) s += t;
    }
    if (lane == 63) wsum[wid] = s;
    __syncthreads();
    int woff = 0;
    for (int w = 0; w < wid; w++) woff += wsum[w];
    int start = woff + s - own;  // exclusive prefix of this thread's first element
    __syncthreads();             // everyone done reading buf as input
    int run = start;
#pragma unroll
    for (int j = 0; j < 8; j++) {
        buf[threadIdx.x * 8 + j] = run;
        run += v[j];
    }
    __syncthreads();
#pragma unroll
    for (int r = 0; r < 8; r++) {
        int i = base + r * 256 + threadIdx.x;
        if (i < n) out[i] = buf[r * 256 + threadIdx.x];
    }
    if (bsum && threadIdx.x == 255) bsum[blockIdx.x] = woff + s;  // block total
}

__global__ __launch_bounds__(256) void k_scan3(int* __restrict__ offs,
                                               const int* __restrict__ bsum, int n) {
    int i = blockIdx.x * 256 + threadIdx.x;
    if (i < n) offs[i] += bsum[blockIdx.x >> 3];  // 8 blocks of 256 per scan chunk
}

// ---- CSR scatter (offs advanced in place; gather recovers start = offs-cnt) ----
__global__ __launch_bounds__(256) void k_scatter1(const int* __restrict__ src,
                                                  const int* __restrict__ dst,
                                                  int* offs1, int* __restrict__ adj1, int E) {
    int e = blockIdx.x * 256 + threadIdx.x;
    if (e >= E) return;
    adj1[atomicAdd(offs1 + dst[e], 1)] = src[e];
}

__global__ __launch_bounds__(256) void k_scatter2(const int* __restrict__ s2,
                                                  const int* __restrict__ d2,
                                                  int* offs2f, int* offs2r,
                                                  int* __restrict__ adj2f,
                                                  int* __restrict__ adj2r, int E) {
    int e = blockIdx.x * 256 + threadIdx.x;
    if (e >= E) return;
    int u = s2[e], v = d2[e];
    adj2f[atomicAdd(offs2f + v, 1)] = u;
    adj2r[atomicAdd(offs2r + u, 1)] = v;
}

// xw1[i] = emb[x[i]] @ W1
__global__ __launch_bounds__(256) void k_xw1(const int* __restrict__ x,
                                             const float* __restrict__ emb,
                                             const float* __restrict__ W1,
                                             float* __restrict__ xw1, int N) {
    int c = threadIdx.x & 31, rg = threadIdx.x >> 5;
    int r0 = blockIdx.x * 32 + rg * 4;
    int xi[4];
    float acc[4] = {0.f, 0.f, 0.f, 0.f};
#pragma unroll
    for (int j = 0; j < 4; j++) {
        int r = r0 + j;
        xi[j] = (r < N) ? x[r] * 64 : 0;  // float4 row base (256 floats)
    }
    const float4* emb4 = (const float4*)emb;
    for (int k = 0; k < 256; k += 4) {
        float w0 = W1[k * 32 + c], w1 = W1[k * 32 + 32 + c];
        float w2 = W1[k * 32 + 64 + c], w3 = W1[k * 32 + 96 + c];
        int kq = k >> 2;
#pragma unroll
        for (int j = 0; j < 4; j++) {
            float4 e = emb4[xi[j] + kq];
            acc[j] = fmaf(e.x, w0, fmaf(e.y, w1, fmaf(e.z, w2, fmaf(e.w, w3, acc[j]))));
        }
    }
#pragma unroll
    for (int j = 0; j < 4; j++) {
        int r = r0 + j;
        if (r < N) xw1[r * 32 + c] = acc[j];
    }
}

// generic GCN gather: out[v] = dv * ( xw[v]*dv + sum_u xw[u]*dinv[u] )
// 8 lanes/node, float4 per lane.
__global__ __launch_bounds__(256) void k_gather(const int* __restrict__ adj,
                                                const int* __restrict__ offs,  // post-scatter = end
                                                const int* __restrict__ cnt,
                                                const float* __restrict__ dinv,
                                                const float* __restrict__ xw,
                                                float* __restrict__ out, int N) {
    int gid = blockIdx.x * 256 + threadIdx.x;
    int v = gid >> 3, q = gid & 7;
    if (v >= N) return;
    int end = offs[v];
    int beg = end - cnt[v];
    float dv = dinv[v];
    const float4* x4 = (const float4*)xw;
    float4 sv = x4[v * 8 + q];
    float4 acc;
    acc.x = sv.x * dv;
    acc.y = sv.y * dv;
    acc.z = sv.z * dv;
    acc.w = sv.w * dv;
    for (int i = beg; i < end; i++) {
        int u = adj[i];
        float du = dinv[u];
        float4 xu = x4[u * 8 + q];
        acc.x = fmaf(xu.x, du, acc.x);
        acc.y = fmaf(xu.y, du, acc.y);
        acc.z = fmaf(xu.z, du, acc.z);
        acc.w = fmaf(xu.w, du, acc.w);
    }
    acc.x *= dv;
    acc.y *= dv;
    acc.z *= dv;
    acc.w *= dv;
    ((float4*)out)[v * 8 + q] = acc;
}

// reverse-direction gather fused with h3 = relu(o2a+b2a)+relu(o2b+b2b), in place over o2a
__global__ __launch_bounds__(256) void k_gather2r(const int* __restrict__ adj,
                                                  const int* __restrict__ offs,
                                                  const int* __restrict__ cnt,
                                                  const float* __restrict__ dinv,
                                                  const float* __restrict__ xw,
                                                  float* __restrict__ h3,  // in: raw o2a, out: h3
                                                  const float* __restrict__ b2a,
                                                  const float* __restrict__ b2b, int N) {
    int gid = blockIdx.x * 256 + threadIdx.x;
    int v = gid >> 3, q = gid & 7;
    if (v >= N) return;
    int end = offs[v];
    int beg = end - cnt[v];
    float dv = dinv[v];
    const float4* x4 = (const float4*)xw;
    float4 sv = x4[v * 8 + q];
    float4 acc;
    acc.x = sv.x * dv;
    acc.y = sv.y * dv;
    acc.z = sv.z * dv;
    acc.w = sv.w * dv;
    for (int i = beg; i < end; i++) {
        int u = adj[i];
        float du = dinv[u];
        float4 xu = x4[u * 8 + q];
        acc.x = fmaf(xu.x, du, acc.x);
        acc.y = fmaf(xu.y, du, acc.y);
        acc.z = fmaf(xu.z, du, acc.z);
        acc.w = fmaf(xu.w, du, acc.w);
    }
    float4 a = ((const float4*)h3)[v * 8 + q];
    float4 ba = ((const float4*)b2a)[q];
    float4 bb = ((const float4*)b2b)[q];
    float4 h;
    h.x = fmaxf(a.x + ba.x, 0.f) + fmaxf(fmaf(acc.x, dv, bb.x), 0.f);
    h.y = fmaxf(a.y + ba.y, 0.f) + fmaxf(fmaf(acc.y, dv, bb.y), 0.f);
    h.z = fmaxf(a.z + ba.z, 0.f) + fmaxf(fmaf(acc.z, dv, bb.z), 0.f);
    h.w = fmaxf(a.w + ba.w, 0.f) + fmaxf(fmaf(acc.w, dv, bb.w), 0.f);
    ((float4*)h3)[v * 8 + q] = h;
}

// hp[p] = relu(out1[pos0]+b1) * relu(out1[pos1]+b1)  (never materialized)
// xwa = hp @ W2a ; xwb = hp @ W2b
__global__ __launch_bounds__(256) void k_xw2(const int* __restrict__ pos,
                                             const float* __restrict__ out1,
                                             const float* __restrict__ b1,
                                             const float* __restrict__ W2a,
                                             const float* __restrict__ W2b,
                                             float* __restrict__ xwa, float* __restrict__ xwb) {
    int c = threadIdx.x & 31, rg = threadIdx.x >> 5;
    int p0 = blockIdx.x * 32 + rg * 4;
    int pa[4], pb[4];
#pragma unroll
    for (int j = 0; j < 4; j++) {
        pa[j] = pos[2 * (p0 + j)] * 8;  // float4 row base of out1
        pb[j] = pos[2 * (p0 + j) + 1] * 8;
    }
    float aa[4] = {0, 0, 0, 0}, ab[4] = {0, 0, 0, 0};
    const float4* o14 = (const float4*)out1;
    const float4* b14 = (const float4*)b1;
    for (int k = 0; k < 32; k += 4) {
        int kq = k >> 2;
        float4 bq = b14[kq];
        float wa0 = W2a[k * 32 + c], wa1 = W2a[k * 32 + 32 + c];
        float wa2 = W2a[k * 32 + 64 + c], wa3 = W2a[k * 32 + 96 + c];
        float wb0 = W2b[k * 32 + c], wb1 = W2b[k * 32 + 32 + c];
        float wb2 = W2b[k * 32 + 64 + c], wb3 = W2b[k * 32 + 96 + c];
#pragma unroll
        for (int j = 0; j < 4; j++) {
            float4 ea = relu4(o14[pa[j] + kq], bq);
            float4 eb = relu4(o14[pb[j] + kq], bq);
            float hx = ea.x * eb.x, hy = ea.y * eb.y, hz = ea.z * eb.z, hw = ea.w * eb.w;
            aa[j] = fmaf(hx, wa0, fmaf(hy, wa1, fmaf(hz, wa2, fmaf(hw, wa3, aa[j]))));
            ab[j] = fmaf(hx, wb0, fmaf(hy, wb1, fmaf(hz, wb2, fmaf(hw, wb3, ab[j]))));
        }
    }
#pragma unroll
    for (int j = 0; j < 4; j++) {
        int p = p0 + j;
        xwa[p * 32 + c] = aa[j];
        xwb[p * 32 + c] = ab[j];
    }
}

// out[q] = (h3[idx[2q]] * h3[idx[2q+1]]) . Wp + bp     8 lanes/output
__global__ __launch_bounds__(256) void k_final(const int* __restrict__ idx,
                                               const float* __restrict__ h3,
                                               const float* __restrict__ Wp,
                                               const float* __restrict__ bp,
                                               float* __restrict__ out, int Q) {
    int gid = blockIdx.x * 256 + threadIdx.x;
    int qi = gid >> 3, q = gid & 7;
    if (qi >= Q) return;
    int i0 = idx[2 * qi] * 8, i1 = idx[2 * qi + 1] * 8;
    float4 wp = ((const float4*)Wp)[q];
    const float4* H = (const float4*)h3;
    float4 h0 = H[i0 + q], h1 = H[i1 + q];
    float s = h0.x * h1.x * wp.x + h0.y * h1.y * wp.y + h0.z * h1.z * wp.z + h0.w * h1.w * wp.w;
    s += __shfl_xor(s, 1);
    s += __shfl_xor(s, 2);
    s += __shfl_xor(s, 4);
    if (q == 0) out[qi] = s + bp[0];
}

// ---------- launch ----------
extern "C" void kernel_launch(void* const* d_in, const int* in_sizes, int n_in,
                              void* d_out, int out_size, void* d_ws, size_t ws_size,
                              hipStream_t stream) {
    const int* x    = (const int*)d_in[0];
    const int* e1   = (const int*)d_in[1];   // [2, E1]
    const int* pos  = (const int*)d_in[2];   // [NP, 2]
    const int* idx  = (const int*)d_in[3];   // [NP]
    const int* e2   = (const int*)d_in[4];   // [2, E2]
    const float* emb = (const float*)d_in[5];
    const float* W1  = (const float*)d_in[6];
    const float* b1  = (const float*)d_in[7];
    const float* W2a = (const float*)d_in[8];
    const float* b2a = (const float*)d_in[9];
    const float* W2b = (const float*)d_in[10];
    const float* b2b = (const float*)d_in[11];
    const float* Wp  = (const float*)d_in[12];
    const float* bp  = (const float*)d_in[13];

    const int N1 = in_sizes[0];      // 50000
    const int E1 = in_sizes[1] / 2;  // 1600000
    const int NP = in_sizes[3];      // 200000
    const int E2 = in_sizes[4] / 2;  // 1600000
    const int Q  = out_size;         // 100000
    (void)n_in; (void)ws_size;

    // ---- workspace layout (bytes), aliased to stay ~101 MB ----
    char* w = (char*)d_ws;
    size_t o = 0;
    auto alloc = [&](size_t bytes) { size_t r = o; o += (bytes + 255) & ~(size_t)255; return r; };
    // cnt region (contiguous for zero/dinv): cnt1 | cnt2f | cnt2r
    int* cnt1  = (int*)(w + alloc((size_t)(N1 + 2 * NP) * 4));
    int* cnt2f = cnt1 + N1;
    int* cnt2r = cnt2f + NP;
    const int nCnt = N1 + 2 * NP;
    // offs region (same internal layout)
    int* offs1  = (int*)(w + alloc((size_t)(N1 + 2 * NP) * 4));
    int* offs2f = offs1 + N1;
    int* offs2r = offs2f + NP;
    // dinv region
    float* dinv1  = (float*)(w + alloc((size_t)(N1 + 2 * NP) * 4));
    float* dinv2f = dinv1 + N1;
    float* dinv2r = dinv2f + NP;
    int* bsum = (int*)(w + alloc(2048 * 4));
    int* adj2f = (int*)(w + alloc((size_t)E2 * 4));
    int* adj2r = (int*)(w + alloc((size_t)E2 * 4));
    float* out1 = (float*)(w + alloc((size_t)N1 * 32 * 4));
    float* xwb  = (float*)(w + alloc((size_t)NP * 32 * 4));
    float* o2a  = (float*)(w + alloc((size_t)NP * 32 * 4));  // becomes h3 in place
    // unionA: [xw1 (N1*128B) | adj1 (E1*4B)] reused later as xwa (NP*128B)
    size_t unionA = alloc((size_t)NP * 32 * 4 > (size_t)N1 * 32 * 4 + (size_t)E1 * 4
                              ? (size_t)NP * 32 * 4
                              : (size_t)N1 * 32 * 4 + (size_t)E1 * 4);
    float* xw1  = (float*)(w + unionA);
    int*   adj1 = (int*)(w + unionA + (size_t)N1 * 32 * 4);
    float* xwa  = (float*)(w + unionA);

    const int B = 256;
    auto cdiv = [](long long a, long long b) { return (int)((a + b - 1) / b); };

    // 1) zero histograms
    k_zero_i<<<cdiv(nCnt, B), B, 0, stream>>>(cnt1, nCnt);
    // 2) degree histograms
    int Emax = E1 > E2 ? E1 : E2;
    k_deg<<<cdiv(Emax, B), B, 0, stream>>>(e1 + E1, e2, e2 + E2, cnt1, cnt2f, cnt2r, E1, E2);
    // 3) dinv = rsqrt(cnt+1)
    k_dinv<<<cdiv(nCnt, B), B, 0, stream>>>(cnt1, dinv1, nCnt);
    // 4) exclusive scans cnt -> offs (x3)
    {
        int nb = cdiv(N1, SCAN_CHUNK);
        k_scan1<<<nb, B, 0, stream>>>(cnt1, offs1, bsum, N1);
        k_scan1<<<1, B, 0, stream>>>(bsum, bsum, nullptr, nb);
        k_scan3<<<cdiv(N1, B), B, 0, stream>>>(offs1, bsum, N1);
        nb = cdiv(NP, SCAN_CHUNK);
        k_scan1<<<nb, B, 0, stream>>>(cnt2f, offs2f, bsum, NP);
        k_scan1<<<1, B, 0, stream>>>(bsum, bsum, nullptr, nb);
        k_scan3<<<cdiv(NP, B), B, 0, stream>>>(offs2f, bsum, NP);
        k_scan1<<<nb, B, 0, stream>>>(cnt2r, offs2r, bsum, NP);
        k_scan1<<<1, B, 0, stream>>>(bsum, bsum, nullptr, nb);
        k_scan3<<<cdiv(NP, B), B, 0, stream>>>(offs2r, bsum, NP);
    }
    // 5) CSR scatters (offs advanced to end-positions)
    k_scatter1<<<cdiv(E1, B), B, 0, stream>>>(e1, e1 + E1, offs1, adj1, E1);
    k_scatter2<<<cdiv(E2, B), B, 0, stream>>>(e2, e2 + E2, offs2f, offs2r, adj2f, adj2r, E2);
    // 6) xw1 = emb[x] @ W1
    k_xw1<<<cdiv(N1, 32), B, 0, stream>>>(x, emb, W1, xw1, N1);
    // 7) GCN1 gather -> out1 (raw, pre-bias/relu)
    k_gather<<<cdiv((long long)N1 * 8, B), B, 0, stream>>>(adj1, offs1, cnt1, dinv1, xw1, out1, N1);
    // 8) pair-product + both GEMMs (xw1/adj1 dead; xwa aliases them)
    k_xw2<<<cdiv(NP, 32), B, 0, stream>>>(pos, out1, b1, W2a, W2b, xwa, xwb);
    // 9) GCN2 forward gather -> o2a (raw)
    k_gather<<<cdiv((long long)NP * 8, B), B, 0, stream>>>(adj2f, offs2f, cnt2f, dinv2f, xwa, o2a, NP);
    // 10) GCN2 reverse gather fused with h3 = relu(o2a+b2a)+relu(o2b+b2b), in place
    k_gather2r<<<cdiv((long long)NP * 8, B), B, 0, stream>>>(adj2r, offs2r, cnt2r, dinv2r, xwb,
                                                             o2a, b2a, b2b, NP);
    // 11) final gather + pair product + projection
    k_final<<<cdiv((long long)Q * 8, B), B, 0, stream>>>(idx, o2a, Wp, bp, (float*)d_out, Q);
}

// Round 3
// 819.674 us; speedup vs baseline: 2.9806x; 1.2365x over previous
//
#include <hip/hip_runtime.h>
#include <math.h>

// ------------------------------------------------------------------
// LocalWLNet: emb-gather+GEMM -> GCN1 -> pair-product+2xGEMM -> GCN2(fwd+rev)
// -> gather+pair-product+projection.
// R3: CSR build (histogram + scatter) made dst-range-partitioned so each
// block group's counters/adj slice stays L2-resident (blockIdx&7 ~ XCD).
// ------------------------------------------------------------------

#define NRANGE 8

static __device__ __forceinline__ float4 relu4(float4 a, float4 b) {  // relu(a+b)
    float4 r;
    r.x = fmaxf(a.x + b.x, 0.f);
    r.y = fmaxf(a.y + b.y, 0.f);
    r.z = fmaxf(a.z + b.z, 0.f);
    r.w = fmaxf(a.w + b.w, 0.f);
    return r;
}

__global__ __launch_bounds__(256) void k_zero_i(int* __restrict__ p, int n) {
    int i = blockIdx.x * 256 + threadIdx.x;
    if (i < n) p[i] = 0;
}

// range-partitioned degree histograms (all three in one pass)
__global__ __launch_bounds__(256) void k_degR(const int* __restrict__ d1,
                                              const int* __restrict__ s2,
                                              const int* __restrict__ d2,
                                              int* c1, int* c2f, int* c2r,
                                              int E1, int E2, int N1, int NP) {
    int g = blockIdx.x & (NRANGE - 1);
    int gblk = blockIdx.x >> 3;
    int ngrp = gridDim.x >> 3;
    int rs1 = (N1 + NRANGE - 1) / NRANGE, lo1 = g * rs1, hi1 = lo1 + rs1;
    int rs2 = (NP + NRANGE - 1) / NRANGE, lo2 = g * rs2, hi2 = lo2 + rs2;
    int Emax = E1 > E2 ? E1 : E2;
    for (int i = gblk * 256 + threadIdx.x; i < Emax; i += ngrp * 256) {
        if (i < E1) {
            int d = d1[i];
            if (d >= lo1 && d < hi1) atomicAdd(c1 + d, 1);
        }
        if (i < E2) {
            int u = s2[i], v = d2[i];
            if (v >= lo2 && v < hi2) atomicAdd(c2f + v, 1);
            if (u >= lo2 && u < hi2) atomicAdd(c2r + u, 1);
        }
    }
}

// dinv = 1/sqrt(cnt + 1)   (+1 = self loop)
__global__ __launch_bounds__(256) void k_dinv(const int* __restrict__ cnt,
                                              float* __restrict__ dinv, int n) {
    int i = blockIdx.x * 256 + threadIdx.x;
    if (i < n) dinv[i] = 1.f / sqrtf((float)cnt[i] + 1.f);
}

// ---- exclusive scan (3-kernel, chunk = 2048 per block) ----
#define SCAN_CHUNK 2048
__global__ __launch_bounds__(256) void k_scan1(const int* __restrict__ in, int* __restrict__ out,
                                               int* __restrict__ bsum, int n) {
    __shared__ int buf[SCAN_CHUNK];
    __shared__ int wsum[4];
    int base = blockIdx.x * SCAN_CHUNK;
#pragma unroll
    for (int r = 0; r < 8; r++) {
        int i = base + r * 256 + threadIdx.x;
        buf[r * 256 + threadIdx.x] = (i < n) ? in[i] : 0;
    }
    __syncthreads();
    int v[8];
    int s = 0;
#pragma unroll
    for (int j = 0; j < 8; j++) {
        v[j] = buf[threadIdx.x * 8 + j];
        s += v[j];
    }
    int own = s;
    int lane = threadIdx.x & 63, wid = threadIdx.x >> 6;
#pragma unroll
    for (int d = 1; d < 64; d <<= 1) {
        int t = __shfl_up(s, d, 64);
        if (lane >= d) s += t;
    }
    if (lane == 63) wsum[wid] = s;
    __syncthreads();
    int woff = 0;
    for (int w = 0; w < wid; w++) woff += wsum[w];
    int start = woff + s - own;  // exclusive prefix of this thread's first element
    __syncthreads();
    int run = start;
#pragma unroll
    for (int j = 0; j < 8; j++) {
        buf[threadIdx.x * 8 + j] = run;
        run += v[j];
    }
    __syncthreads();
#pragma unroll
    for (int r = 0; r < 8; r++) {
        int i = base + r * 256 + threadIdx.x;
        if (i < n) out[i] = buf[r * 256 + threadIdx.x];
    }
    if (bsum && threadIdx.x == 255) bsum[blockIdx.x] = woff + s;  // block total
}

__global__ __launch_bounds__(256) void k_scan3(int* __restrict__ offs,
                                               const int* __restrict__ bsum, int n) {
    int i = blockIdx.x * 256 + threadIdx.x;
    if (i < n) offs[i] += bsum[blockIdx.x >> 3];  // 8 blocks of 256 per scan chunk
}

// ---- range-partitioned CSR scatters (offs advanced in place) ----
__global__ __launch_bounds__(256) void k_scatter1R(const int* __restrict__ src,
                                                   const int* __restrict__ dst,
                                                   int* offs1, int* __restrict__ adj1,
                                                   int E, int N) {
    int g = blockIdx.x & (NRANGE - 1);
    int gblk = blockIdx.x >> 3;
    int ngrp = gridDim.x >> 3;
    int rs = (N + NRANGE - 1) / NRANGE, lo = g * rs, hi = lo + rs;
    for (int e = gblk * 256 + threadIdx.x; e < E; e += ngrp * 256) {
        int d = dst[e];
        if (d >= lo && d < hi) adj1[atomicAdd(offs1 + d, 1)] = src[e];
    }
}

__global__ __launch_bounds__(256) void k_scatter2R(const int* __restrict__ s2,
                                                   const int* __restrict__ d2,
                                                   int* offs2f, int* offs2r,
                                                   int* __restrict__ adj2f,
                                                   int* __restrict__ adj2r, int E, int N) {
    int g = blockIdx.x & (NRANGE - 1);
    int gblk = blockIdx.x >> 3;
    int ngrp = gridDim.x >> 3;
    int rs = (N + NRANGE - 1) / NRANGE, lo = g * rs, hi = lo + rs;
    for (int e = gblk * 256 + threadIdx.x; e < E; e += ngrp * 256) {
        int u = s2[e], v = d2[e];
        if (v >= lo && v < hi) adj2f[atomicAdd(offs2f + v, 1)] = u;
        if (u >= lo && u < hi) adj2r[atomicAdd(offs2r + u, 1)] = v;
    }
}

// xw1[i] = emb[x[i]] @ W1
__global__ __launch_bounds__(256) void k_xw1(const int* __restrict__ x,
                                             const float* __restrict__ emb,
                                             const float* __restrict__ W1,
                                             float* __restrict__ xw1, int N) {
    int c = threadIdx.x & 31, rg = threadIdx.x >> 5;
    int r0 = blockIdx.x * 32 + rg * 4;
    int xi[4];
    float acc[4] = {0.f, 0.f, 0.f, 0.f};
#pragma unroll
    for (int j = 0; j < 4; j++) {
        int r = r0 + j;
        xi[j] = (r < N) ? x[r] * 64 : 0;  // float4 row base (256 floats)
    }
    const float4* emb4 = (const float4*)emb;
    for (int k = 0; k < 256; k += 4) {
        float w0 = W1[k * 32 + c], w1 = W1[k * 32 + 32 + c];
        float w2 = W1[k * 32 + 64 + c], w3 = W1[k * 32 + 96 + c];
        int kq = k >> 2;
#pragma unroll
        for (int j = 0; j < 4; j++) {
            float4 e = emb4[xi[j] + kq];
            acc[j] = fmaf(e.x, w0, fmaf(e.y, w1, fmaf(e.z, w2, fmaf(e.w, w3, acc[j]))));
        }
    }
#pragma unroll
    for (int j = 0; j < 4; j++) {
        int r = r0 + j;
        if (r < N) xw1[r * 32 + c] = acc[j];
    }
}

// generic GCN gather: out[v] = dv * ( xw[v]*dv + sum_u xw[u]*dinv[u] )
// 8 lanes/node, float4 per lane.
__global__ __launch_bounds__(256) void k_gather(const int* __restrict__ adj,
                                                const int* __restrict__ offs,  // post-scatter = end
                                                const int* __restrict__ cnt,
                                                const float* __restrict__ dinv,
                                                const float* __restrict__ xw,
                                                float* __restrict__ out, int N) {
    int gid = blockIdx.x * 256 + threadIdx.x;
    int v = gid >> 3, q = gid & 7;
    if (v >= N) return;
    int end = offs[v];
    int beg = end - cnt[v];
    float dv = dinv[v];
    const float4* x4 = (const float4*)xw;
    float4 sv = x4[v * 8 + q];
    float4 acc;
    acc.x = sv.x * dv;
    acc.y = sv.y * dv;
    acc.z = sv.z * dv;
    acc.w = sv.w * dv;
    for (int i = beg; i < end; i++) {
        int u = adj[i];
        float du = dinv[u];
        float4 xu = x4[u * 8 + q];
        acc.x = fmaf(xu.x, du, acc.x);
        acc.y = fmaf(xu.y, du, acc.y);
        acc.z = fmaf(xu.z, du, acc.z);
        acc.w = fmaf(xu.w, du, acc.w);
    }
    acc.x *= dv;
    acc.y *= dv;
    acc.z *= dv;
    acc.w *= dv;
    ((float4*)out)[v * 8 + q] = acc;
}

// reverse-direction gather fused with h3 = relu(o2a+b2a)+relu(o2b+b2b), in place over o2a
__global__ __launch_bounds__(256) void k_gather2r(const int* __restrict__ adj,
                                                  const int* __restrict__ offs,
                                                  const int* __restrict__ cnt,
                                                  const float* __restrict__ dinv,
                                                  const float* __restrict__ xw,
                                                  float* __restrict__ h3,  // in: raw o2a, out: h3
                                                  const float* __restrict__ b2a,
                                                  const float* __restrict__ b2b, int N) {
    int gid = blockIdx.x * 256 + threadIdx.x;
    int v = gid >> 3, q = gid & 7;
    if (v >= N) return;
    int end = offs[v];
    int beg = end - cnt[v];
    float dv = dinv[v];
    const float4* x4 = (const float4*)xw;
    float4 sv = x4[v * 8 + q];
    float4 acc;
    acc.x = sv.x * dv;
    acc.y = sv.y * dv;
    acc.z = sv.z * dv;
    acc.w = sv.w * dv;
    for (int i = beg; i < end; i++) {
        int u = adj[i];
        float du = dinv[u];
        float4 xu = x4[u * 8 + q];
        acc.x = fmaf(xu.x, du, acc.x);
        acc.y = fmaf(xu.y, du, acc.y);
        acc.z = fmaf(xu.z, du, acc.z);
        acc.w = fmaf(xu.w, du, acc.w);
    }
    float4 a = ((const float4*)h3)[v * 8 + q];
    float4 ba = ((const float4*)b2a)[q];
    float4 bb = ((const float4*)b2b)[q];
    float4 h;
    h.x = fmaxf(a.x + ba.x, 0.f) + fmaxf(fmaf(acc.x, dv, bb.x), 0.f);
    h.y = fmaxf(a.y + ba.y, 0.f) + fmaxf(fmaf(acc.y, dv, bb.y), 0.f);
    h.z = fmaxf(a.z + ba.z, 0.f) + fmaxf(fmaf(acc.z, dv, bb.z), 0.f);
    h.w = fmaxf(a.w + ba.w, 0.f) + fmaxf(fmaf(acc.w, dv, bb.w), 0.f);
    ((float4*)h3)[v * 8 + q] = h;
}

// hp[p] = relu(out1[pos0]+b1) * relu(out1[pos1]+b1)  (never materialized)
// xwa = hp @ W2a ; xwb = hp @ W2b
__global__ __launch_bounds__(256) void k_xw2(const int* __restrict__ pos,
                                             const float* __restrict__ out1,
                                             const float* __restrict__ b1,
                                             const float* __restrict__ W2a,
                                             const float* __restrict__ W2b,
                                             float* __restrict__ xwa, float* __restrict__ xwb) {
    int c = threadIdx.x & 31, rg = threadIdx.x >> 5;
    int p0 = blockIdx.x * 32 + rg * 4;
    int pa[4], pb[4];
#pragma unroll
    for (int j = 0; j < 4; j++) {
        pa[j] = pos[2 * (p0 + j)] * 8;  // float4 row base of out1
        pb[j] = pos[2 * (p0 + j) + 1] * 8;
    }
    float aa[4] = {0, 0, 0, 0}, ab[4] = {0, 0, 0, 0};
    const float4* o14 = (const float4*)out1;
    const float4* b14 = (const float4*)b1;
    for (int k = 0; k < 32; k += 4) {
        int kq = k >> 2;
        float4 bq = b14[kq];
        float wa0 = W2a[k * 32 + c], wa1 = W2a[k * 32 + 32 + c];
        float wa2 = W2a[k * 32 + 64 + c], wa3 = W2a[k * 32 + 96 + c];
        float wb0 = W2b[k * 32 + c], wb1 = W2b[k * 32 + 32 + c];
        float wb2 = W2b[k * 32 + 64 + c], wb3 = W2b[k * 32 + 96 + c];
#pragma unroll
        for (int j = 0; j < 4; j++) {
            float4 ea = relu4(o14[pa[j] + kq], bq);
            float4 eb = relu4(o14[pb[j] + kq], bq);
            float hx = ea.x * eb.x, hy = ea.y * eb.y, hz = ea.z * eb.z, hw = ea.w * eb.w;
            aa[j] = fmaf(hx, wa0, fmaf(hy, wa1, fmaf(hz, wa2, fmaf(hw, wa3, aa[j]))));
            ab[j] = fmaf(hx, wb0, fmaf(hy, wb1, fmaf(hz, wb2, fmaf(hw, wb3, ab[j]))));
        }
    }
#pragma unroll
    for (int j = 0; j < 4; j++) {
        int p = p0 + j;
        xwa[p * 32 + c] = aa[j];
        xwb[p * 32 + c] = ab[j];
    }
}

// out[q] = (h3[idx[2q]] * h3[idx[2q+1]]) . Wp + bp     8 lanes/output
__global__ __launch_bounds__(256) void k_final(const int* __restrict__ idx,
                                               const float* __restrict__ h3,
                                               const float* __restrict__ Wp,
                                               const float* __restrict__ bp,
                                               float* __restrict__ out, int Q) {
    int gid = blockIdx.x * 256 + threadIdx.x;
    int qi = gid >> 3, q = gid & 7;
    if (qi >= Q) return;
    int i0 = idx[2 * qi] * 8, i1 = idx[2 * qi + 1] * 8;
    float4 wp = ((const float4*)Wp)[q];
    const float4* H = (const float4*)h3;
    float4 h0 = H[i0 + q], h1 = H[i1 + q];
    float s = h0.x * h1.x * wp.x + h0.y * h1.y * wp.y + h0.z * h1.z * wp.z + h0.w * h1.w * wp.w;
    s += __shfl_xor(s, 1);
    s += __shfl_xor(s, 2);
    s += __shfl_xor(s, 4);
    if (q == 0) out[qi] = s + bp[0];
}

// ---------- launch ----------
extern "C" void kernel_launch(void* const* d_in, const int* in_sizes, int n_in,
                              void* d_out, int out_size, void* d_ws, size_t ws_size,
                              hipStream_t stream) {
    const int* x    = (const int*)d_in[0];
    const int* e1   = (const int*)d_in[1];   // [2, E1]
    const int* pos  = (const int*)d_in[2];   // [NP, 2]
    const int* idx  = (const int*)d_in[3];   // [NP]
    const int* e2   = (const int*)d_in[4];   // [2, E2]
    const float* emb = (const float*)d_in[5];
    const float* W1  = (const float*)d_in[6];
    const float* b1  = (const float*)d_in[7];
    const float* W2a = (const float*)d_in[8];
    const float* b2a = (const float*)d_in[9];
    const float* W2b = (const float*)d_in[10];
    const float* b2b = (const float*)d_in[11];
    const float* Wp  = (const float*)d_in[12];
    const float* bp  = (const float*)d_in[13];

    const int N1 = in_sizes[0];      // 50000
    const int E1 = in_sizes[1] / 2;  // 1600000
    const int NP = in_sizes[3];      // 200000
    const int E2 = in_sizes[4] / 2;  // 1600000
    const int Q  = out_size;         // 100000
    (void)n_in; (void)ws_size;

    // ---- workspace layout (bytes), aliased to stay ~101 MB ----
    char* w = (char*)d_ws;
    size_t o = 0;
    auto alloc = [&](size_t bytes) { size_t r = o; o += (bytes + 255) & ~(size_t)255; return r; };
    // cnt region (contiguous for zero/dinv): cnt1 | cnt2f | cnt2r
    int* cnt1  = (int*)(w + alloc((size_t)(N1 + 2 * NP) * 4));
    int* cnt2f = cnt1 + N1;
    int* cnt2r = cnt2f + NP;
    const int nCnt = N1 + 2 * NP;
    // offs region (same internal layout)
    int* offs1  = (int*)(w + alloc((size_t)(N1 + 2 * NP) * 4));
    int* offs2f = offs1 + N1;
    int* offs2r = offs2f + NP;
    // dinv region
    float* dinv1  = (float*)(w + alloc((size_t)(N1 + 2 * NP) * 4));
    float* dinv2f = dinv1 + N1;
    float* dinv2r = dinv2f + NP;
    int* bsum = (int*)(w + alloc(2048 * 4));
    int* adj2f = (int*)(w + alloc((size_t)E2 * 4));
    int* adj2r = (int*)(w + alloc((size_t)E2 * 4));
    float* out1 = (float*)(w + alloc((size_t)N1 * 32 * 4));
    float* xwb  = (float*)(w + alloc((size_t)NP * 32 * 4));
    float* o2a  = (float*)(w + alloc((size_t)NP * 32 * 4));  // becomes h3 in place
    // unionA: [xw1 (N1*128B) | adj1 (E1*4B)] reused later as xwa (NP*128B)
    size_t unionA = alloc((size_t)NP * 32 * 4 > (size_t)N1 * 32 * 4 + (size_t)E1 * 4
                              ? (size_t)NP * 32 * 4
                              : (size_t)N1 * 32 * 4 + (size_t)E1 * 4);
    float* xw1  = (float*)(w + unionA);
    int*   adj1 = (int*)(w + unionA + (size_t)N1 * 32 * 4);
    float* xwa  = (float*)(w + unionA);

    const int B = 256;
    auto cdiv = [](long long a, long long b) { return (int)((a + b - 1) / b); };
    const int SCAT_GRID = 1024;  // 8 ranges x 128 blocks

    // 1) zero histograms
    k_zero_i<<<cdiv(nCnt, B), B, 0, stream>>>(cnt1, nCnt);
    // 2) degree histograms (range-partitioned)
    k_degR<<<SCAT_GRID, B, 0, stream>>>(e1 + E1, e2, e2 + E2, cnt1, cnt2f, cnt2r,
                                        E1, E2, N1, NP);
    // 3) dinv = rsqrt(cnt+1)
    k_dinv<<<cdiv(nCnt, B), B, 0, stream>>>(cnt1, dinv1, nCnt);
    // 4) exclusive scans cnt -> offs (x3)
    {
        int nb = cdiv(N1, SCAN_CHUNK);
        k_scan1<<<nb, B, 0, stream>>>(cnt1, offs1, bsum, N1);
        k_scan1<<<1, B, 0, stream>>>(bsum, bsum, nullptr, nb);
        k_scan3<<<cdiv(N1, B), B, 0, stream>>>(offs1, bsum, N1);
        nb = cdiv(NP, SCAN_CHUNK);
        k_scan1<<<nb, B, 0, stream>>>(cnt2f, offs2f, bsum, NP);
        k_scan1<<<1, B, 0, stream>>>(bsum, bsum, nullptr, nb);
        k_scan3<<<cdiv(NP, B), B, 0, stream>>>(offs2f, bsum, NP);
        k_scan1<<<nb, B, 0, stream>>>(cnt2r, offs2r, bsum, NP);
        k_scan1<<<1, B, 0, stream>>>(bsum, bsum, nullptr, nb);
        k_scan3<<<cdiv(NP, B), B, 0, stream>>>(offs2r, bsum, NP);
    }
    // 5) CSR scatters (range-partitioned; offs advanced to end-positions)
    k_scatter1R<<<SCAT_GRID, B, 0, stream>>>(e1, e1 + E1, offs1, adj1, E1, N1);
    k_scatter2R<<<SCAT_GRID, B, 0, stream>>>(e2, e2 + E2, offs2f, offs2r, adj2f, adj2r, E2, NP);
    // 6) xw1 = emb[x] @ W1
    k_xw1<<<cdiv(N1, 32), B, 0, stream>>>(x, emb, W1, xw1, N1);
    // 7) GCN1 gather -> out1 (raw, pre-bias/relu)
    k_gather<<<cdiv((long long)N1 * 8, B), B, 0, stream>>>(adj1, offs1, cnt1, dinv1, xw1, out1, N1);
    // 8) pair-product + both GEMMs (xw1/adj1 dead; xwa aliases them)
    k_xw2<<<cdiv(NP, 32), B, 0, stream>>>(pos, out1, b1, W2a, W2b, xwa, xwb);
    // 9) GCN2 forward gather -> o2a (raw)
    k_gather<<<cdiv((long long)NP * 8, B), B, 0, stream>>>(adj2f, offs2f, cnt2f, dinv2f, xwa, o2a, NP);
    // 10) GCN2 reverse gather fused with h3 = relu(o2a+b2a)+relu(o2b+b2b), in place
    k_gather2r<<<cdiv((long long)NP * 8, B), B, 0, stream>>>(adj2r, offs2r, cnt2r, dinv2r, xwb,
                                                             o2a, b2a, b2b, NP);
    // 11) final gather + pair product + projection
    k_final<<<cdiv((long long)Q * 8, B), B, 0, stream>>>(idx, o2a, Wp, bp, (float*)d_out, Q);
}